// Round 6
// baseline (202.667 us; speedup 1.0000x reference)
//
#include <hip/hip_runtime.h>
#include <hip/hip_bf16.h>

// NerTr fused pipeline for MI355X (gfx950).  B=32, S=512, D=768, C=25.
// ws layout (bytes): decb (bf16 32*25*768) [0, 1228800); wt (f32 25*768) [1228800, 1305600);
//                    ner (f32 32*512*25) [1305600, 2944000); pqb (bf16 32*512*768) [2944000, 28109824).
// out: [0]=loss (f32), [1 + b*512 + t] = viterbi tag (as f32).

#define NEGINF (-1e30f)

__device__ __forceinline__ float wsum(float v) {
#pragma unroll
  for (int m = 32; m >= 1; m >>= 1) v += __shfl_xor(v, m);
  return v;
}
__device__ __forceinline__ float wmax(float v) {
#pragma unroll
  for (int m = 32; m >= 1; m >>= 1) v = fmaxf(v, __shfl_xor(v, m));
  return v;
}
// SALU broadcast of lane0 (no LDS pipe)
__device__ __forceinline__ float rfl(float x) {
  return __int_as_float(__builtin_amdgcn_readfirstlane(__float_as_int(x)));
}
// uniform readlane (VALU->SGPR, no LDS pipe)
__device__ __forceinline__ float rlane(float x, int i) {
  return __int_as_float(__builtin_amdgcn_readlane(__float_as_int(x), i));
}
__device__ __forceinline__ ushort f2bf(float x) {
  __hip_bfloat16 h = __float2bfloat16(x);  // RTNE
  return *reinterpret_cast<ushort*>(&h);
}
// 12 contiguous-by-lane floats: elements (lane + k*64)*4 .. +3
__device__ __forceinline__ void ld12(float* x, const float* p, int lane) {
#pragma unroll
  for (int k = 0; k < 3; k++) {
    float4 v = *(const float4*)(p + (lane + (k << 6)) * 4);
    x[4 * k + 0] = v.x; x[4 * k + 1] = v.y; x[4 * k + 2] = v.z; x[4 * k + 3] = v.w;
  }
}

// in-register argmax over 25 values, first-index tie-break (jnp.argmax semantics)
__device__ __forceinline__ void argmax25(const float c[25], float& bv, int& bi) {
  float v[13]; int x[13];
#pragma unroll
  for (int i = 0; i < 12; i++) {
    bool t = c[2 * i + 1] > c[2 * i];
    v[i] = t ? c[2 * i + 1] : c[2 * i];
    x[i] = t ? 2 * i + 1 : 2 * i;
  }
  v[12] = c[24]; x[12] = 24;
  float w[7]; int y[7];
#pragma unroll
  for (int i = 0; i < 6; i++) {
    bool t = v[2 * i + 1] > v[2 * i];
    w[i] = t ? v[2 * i + 1] : v[2 * i];
    y[i] = t ? x[2 * i + 1] : x[2 * i];
  }
  w[6] = v[12]; y[6] = x[12];
  float u[4]; int z[4];
#pragma unroll
  for (int i = 0; i < 3; i++) {
    bool t = w[2 * i + 1] > w[2 * i];
    u[i] = t ? w[2 * i + 1] : w[2 * i];
    z[i] = t ? y[2 * i + 1] : y[2 * i];
  }
  u[3] = w[6]; z[3] = y[6];
  bool t0 = u[1] > u[0]; float a = t0 ? u[1] : u[0]; int ai = t0 ? z[1] : z[0];
  bool t1 = u[3] > u[2]; float b = t1 ? u[3] : u[2]; int bj = t1 ? z[3] : z[2];
  bool t2 = b > a; bv = t2 ? b : a; bi = t2 ? bj : ai;
}

// ---------------- Kernel 1: LN(decoder_embedding)->bf16 + transpose W ----------------
__global__ __launch_bounds__(256) void prep_kernel(
    const float* __restrict__ decemb, const float* __restrict__ gamma,
    const float* __restrict__ beta, const float* __restrict__ Wadd,
    ushort* __restrict__ decb, float* __restrict__ wt) {
  const int blk = blockIdx.x;
  const int tid = threadIdx.x;
  if (blk < 800) {  // one block per (b,c) row of decoder_embedding
    const float* in = decemb + (size_t)blk * 768;
    float x0 = in[tid], x1 = in[tid + 256], x2 = in[tid + 512];
    float s = x0 + x1 + x2, q = x0 * x0 + x1 * x1 + x2 * x2;
    float ws_ = wsum(s), wq = wsum(q);
    __shared__ float sa[4], sq[4];
    int w = tid >> 6, ln = tid & 63;
    if (ln == 0) { sa[w] = ws_; sq[w] = wq; }
    __syncthreads();
    float s1 = sa[0] + sa[1] + sa[2] + sa[3];
    float s2 = sq[0] + sq[1] + sq[2] + sq[3];
    float mean = s1 * (1.f / 768.f);
    float rstd = rsqrtf(s2 * (1.f / 768.f) - mean * mean + 1e-5f);
    ushort* o = decb + (size_t)blk * 768;
    o[tid]       = f2bf((x0 - mean) * rstd * gamma[tid]       + beta[tid]);
    o[tid + 256] = f2bf((x1 - mean) * rstd * gamma[tid + 256] + beta[tid + 256]);
    o[tid + 512] = f2bf((x2 - mean) * rstd * gamma[tid + 512] + beta[tid + 512]);
  } else {  // transpose W_add [768,25] -> Wt [25,768]
    int gid = (blk - 800) * 256 + tid;
    for (int e = gid; e < 19200; e += 32 * 256) {
      int d = e / 25, j = e - d * 25;
      wt[j * 768 + d] = Wadd[e];
    }
  }
}

// ---------------- Kernel 2: pq = cos_sim @ dec  -> bf16 (LDS-staged dec, 4 rows/wave) ----------------
__global__ __launch_bounds__(256) void pq_kernel(
    const float* __restrict__ cosim, const ushort* __restrict__ decb,
    ushort* __restrict__ pqb) {
  __shared__ ushort sdec[19200];  // dec[b] bf16, 38400 B
  const int tid = threadIdx.x;
  const int lane = tid & 63;
  const int wid = tid >> 6;
  // bijective XCD swizzle (1024 = 8 x 128)
  const int swz = (blockIdx.x & 7) * 128 + (blockIdx.x >> 3);
  const int b = swz >> 5;                              // 32 blocks per batch
  const int row0 = ((swz & 31) << 4) + (wid << 2);     // 16 rows/block, 4/wave
  const int rowg = b * 512 + row0;

  {
    const uint4* src = (const uint4*)(decb + (size_t)b * 19200);
    uint4* dst = (uint4*)sdec;
#pragma unroll
    for (int i = 0; i < 10; i++) {
      int e = tid + (i << 8);
      if (e < 2400) dst[e] = src[e];
    }
  }
  float cs[4];
#pragma unroll
  for (int r = 0; r < 4; r++)
    cs[r] = (lane < 25) ? cosim[(size_t)(rowg + r) * 25 + lane] : 0.f;
  __syncthreads();

  float pq[4][12];
#pragma unroll
  for (int r = 0; r < 4; r++)
#pragma unroll
    for (int e = 0; e < 12; e++) pq[r][e] = 0.f;
  const char* sd = (const char*)sdec;
#pragma unroll 5
  for (int c = 0; c < 25; c++) {
    uint2 d0 = *(const uint2*)(sd + c * 1536 + lane * 8);
    uint2 d1 = *(const uint2*)(sd + c * 1536 + lane * 8 + 512);
    uint2 d2 = *(const uint2*)(sd + c * 1536 + lane * 8 + 1024);
    float dv[12];
    dv[0]  = __uint_as_float(d0.x << 16); dv[1]  = __uint_as_float(d0.x & 0xffff0000u);
    dv[2]  = __uint_as_float(d0.y << 16); dv[3]  = __uint_as_float(d0.y & 0xffff0000u);
    dv[4]  = __uint_as_float(d1.x << 16); dv[5]  = __uint_as_float(d1.x & 0xffff0000u);
    dv[6]  = __uint_as_float(d1.y << 16); dv[7]  = __uint_as_float(d1.y & 0xffff0000u);
    dv[8]  = __uint_as_float(d2.x << 16); dv[9]  = __uint_as_float(d2.x & 0xffff0000u);
    dv[10] = __uint_as_float(d2.y << 16); dv[11] = __uint_as_float(d2.y & 0xffff0000u);
    float f0 = rlane(cs[0], c), f1 = rlane(cs[1], c);
    float f2 = rlane(cs[2], c), f3 = rlane(cs[3], c);
#pragma unroll
    for (int e = 0; e < 12; e++) {
      pq[0][e] = fmaf(f0, dv[e], pq[0][e]);
      pq[1][e] = fmaf(f1, dv[e], pq[1][e]);
      pq[2][e] = fmaf(f2, dv[e], pq[2][e]);
      pq[3][e] = fmaf(f3, dv[e], pq[3][e]);
    }
  }
  // write bf16, layout matches ld12's (lane + k*64)*4 element order
#pragma unroll
  for (int r = 0; r < 4; r++) {
    ushort* pr = pqb + (size_t)(rowg + r) * 768;
#pragma unroll
    for (int k = 0; k < 3; k++) {
      uint2 u;
      u.x = (uint)f2bf(pq[r][4 * k + 0]) | ((uint)f2bf(pq[r][4 * k + 1]) << 16);
      u.y = (uint)f2bf(pq[r][4 * k + 2]) | ((uint)f2bf(pq[r][4 * k + 3]) << 16);
      *(uint2*)(pr + (lane + (k << 6)) * 4) = u;
    }
  }
}

// ---------------- Kernel 3: streaming LN/add/LN/logits (2 rows/wave, lean regs) ----------------
__global__ __launch_bounds__(256) void main_kernel(
    const float* __restrict__ bert, const float* __restrict__ oenc,
    const ushort* __restrict__ pqb, const float* __restrict__ gamma,
    const float* __restrict__ beta, const float* __restrict__ badd,
    const float* __restrict__ wt,
    float* __restrict__ ner, float* __restrict__ out) {
  __shared__ ushort sred[4][1728];  // per-wave [25][68] bf16 reduce scratch
  const int tid = threadIdx.x;
  const int lane = tid & 63;
  const int wid = tid >> 6;
  if (blockIdx.x == 0 && tid == 0) out[0] = 0.f;  // loss accumulator (scan adds later)

  // bijective XCD swizzle (2048 = 8 x 256)
  const int swz = (blockIdx.x & 7) * 256 + (blockIdx.x >> 3);
  const int b = swz >> 6;
  const int rowg = b * 512 + ((swz & 63) << 3) + (wid << 1);  // 8 rows/block, 2/wave

  float g[12], bbv[12];
  ld12(g, gamma, lane);
  ld12(bbv, beta, lane);

  float acc[2][12];
  ld12(acc[0], bert + (size_t)(rowg + 0) * 768, lane);
  ld12(acc[1], bert + (size_t)(rowg + 1) * 768, lane);

  // Phase A: acc = LN(bert)
#pragma unroll
  for (int r = 0; r < 2; r++) {
    float s = 0.f, q = 0.f;
#pragma unroll
    for (int e = 0; e < 12; e++) { s += acc[r][e]; q += acc[r][e] * acc[r][e]; }
    s = wsum(s); q = wsum(q);
    float mean = s * (1.f / 768.f);
    float rstd = rsqrtf(q * (1.f / 768.f) - mean * mean + 1e-5f);
#pragma unroll
    for (int e = 0; e < 12; e++) acc[r][e] = (acc[r][e] - mean) * rstd * g[e] + bbv[e];
  }

  // += oenc (sequential: y dies after each add)
#pragma unroll
  for (int r = 0; r < 2; r++) {
    float y[12];
    ld12(y, oenc + (size_t)(rowg + r) * 768, lane);
#pragma unroll
    for (int e = 0; e < 12; e++) acc[r][e] += y[e];
  }
  // += pq (bf16)
#pragma unroll
  for (int r = 0; r < 2; r++) {
    const ushort* pr = pqb + (size_t)(rowg + r) * 768;
#pragma unroll
    for (int k = 0; k < 3; k++) {
      uint2 u = *(const uint2*)(pr + (lane + (k << 6)) * 4);
      acc[r][4 * k + 0] += __uint_as_float(u.x << 16);
      acc[r][4 * k + 1] += __uint_as_float(u.x & 0xffff0000u);
      acc[r][4 * k + 2] += __uint_as_float(u.y << 16);
      acc[r][4 * k + 3] += __uint_as_float(u.y & 0xffff0000u);
    }
  }

  // Phase C: acc = relu(LN(acc))
#pragma unroll
  for (int r = 0; r < 2; r++) {
    float s = 0.f, q = 0.f;
#pragma unroll
    for (int e = 0; e < 12; e++) { s += acc[r][e]; q += acc[r][e] * acc[r][e]; }
    s = wsum(s); q = wsum(q);
    float mean = s * (1.f / 768.f);
    float rstd = rsqrtf(q * (1.f / 768.f) - mean * mean + 1e-5f);
#pragma unroll
    for (int e = 0; e < 12; e++)
      acc[r][e] = fmaxf((acc[r][e] - mean) * rstd * g[e] + bbv[e], 0.f);
  }

  // Phase D: logits = emb @ W + b -> log_softmax -> ner
  float p[2][25];
#pragma unroll
  for (int r = 0; r < 2; r++)
#pragma unroll
    for (int j = 0; j < 25; j++) p[r][j] = 0.f;
#pragma unroll 2
  for (int j = 0; j < 25; j++) {
    float wv[12];
    ld12(wv, wt + j * 768, lane);
#pragma unroll
    for (int e = 0; e < 12; e++) {
      p[0][j] = fmaf(acc[0][e], wv[e], p[0][j]);
      p[1][j] = fmaf(acc[1][e], wv[e], p[1][j]);
    }
  }
  // cross-lane reduce via wave-private bf16 scratch (wave-synchronous LDS)
  ushort* scw = sred[wid];
  float bav = (lane < 25) ? badd[lane] : 0.f;
  const int jj = (lane < 25) ? lane : 24;
#pragma unroll
  for (int r = 0; r < 2; r++) {
#pragma unroll
    for (int j = 0; j < 25; j++) scw[j * 68 + lane] = f2bf(p[r][j]);
    float lg = bav;
#pragma unroll
    for (int i = 0; i < 16; i++) {
      uint2 u = *(const uint2*)(scw + jj * 68 + i * 4);
      lg += __uint_as_float(u.x << 16);
      lg += __uint_as_float(u.x & 0xffff0000u);
      lg += __uint_as_float(u.y << 16);
      lg += __uint_as_float(u.y & 0xffff0000u);
    }
    float v = (lane < 25) ? lg : NEGINF;
    float m = wmax(v);
    float e = __expf(v - m);
    float s = wsum(e);
    float lp = v - m - __logf(s);
    if (lane < 25) ner[(size_t)(rowg + r) * 25 + lane] = lp;
  }
}

// ---------------- Kernel 4: CRF (blocks 0..31) + Viterbi (blocks 32..63) ----------------
// All sequential chains use v_readlane (VALU) — zero ds_bpermute on the critical path.
__global__ __launch_bounds__(256) void scan_kernel(
    const float* __restrict__ ner, const float* __restrict__ cosim,
    const int* __restrict__ labels,
    const float* __restrict__ startt, const float* __restrict__ endt,
    const float* __restrict__ trans, float* __restrict__ out) {
  const int tid = threadIdx.x, lane = tid & 63, wid = tid >> 6;
  const int blk = blockIdx.x;
  __shared__ __align__(16) unsigned char shraw[64768];

  if (blk < 32) {
    // ======== CRF NLL for batch b ========
    const int b = blk;
    const float* nb = ner + (size_t)b * 512 * 25;
    float* fV = (float*)shraw;
    float* bV = fV + 32;
    float* s_num = bV + 32;
    if (wid == 0) {
      float Mc[25];  // exp(trans[i][lane])
#pragma unroll
      for (int i = 0; i < 25; i++) Mc[i] = (lane < 25) ? __expf(trans[i * 25 + lane]) : 0.f;
      float sc = (lane < 25) ? startt[lane] + nb[lane] : NEGINF;
      float em = (lane < 25) ? nb[25 + lane] : 0.f;
      for (int t = 1; t <= 256; t++) {
        float emn = (t < 256 && lane < 25) ? nb[(t + 1) * 25 + lane] : 0.f;
        float ms = rfl(sc);
        float E = __expf(sc - ms);
        float a0 = 0, a1 = 0, a2 = 0, a3 = 0, a4 = 0;
#pragma unroll
        for (int i = 0; i < 25; i += 5) {
          a0 = fmaf(rlane(E, i + 0), Mc[i + 0], a0);
          a1 = fmaf(rlane(E, i + 1), Mc[i + 1], a1);
          a2 = fmaf(rlane(E, i + 2), Mc[i + 2], a2);
          a3 = fmaf(rlane(E, i + 3), Mc[i + 3], a3);
          a4 = fmaf(rlane(E, i + 4), Mc[i + 4], a4);
        }
        float acc = ((a0 + a1) + (a2 + a3)) + a4;
        sc = (lane < 25) ? ms + __logf(acc) + em : NEGINF;
        em = emn;
      }
      if (lane < 25) fV[lane] = sc;
    } else if (wid == 1) {
      float MrE[25];  // exp(trans[lane][j])
#pragma unroll
      for (int j = 0; j < 25; j++) MrE[j] = (lane < 25) ? __expf(trans[lane * 25 + j]) : 0.f;
      float bwd = (lane < 25) ? endt[lane] : NEGINF;
      float em = (lane < 25) ? nb[511 * 25 + lane] : 0.f;
      for (int t = 511; t >= 257; t--) {
        float emn = (t > 257 && lane < 25) ? nb[(t - 1) * 25 + lane] : 0.f;
        float u = (lane < 25) ? bwd + em : NEGINF;
        float ms = rfl(u);
        float E = __expf(u - ms);
        float a0 = 0, a1 = 0, a2 = 0, a3 = 0, a4 = 0;
#pragma unroll
        for (int j = 0; j < 25; j += 5) {
          a0 = fmaf(rlane(E, j + 0), MrE[j + 0], a0);
          a1 = fmaf(rlane(E, j + 1), MrE[j + 1], a1);
          a2 = fmaf(rlane(E, j + 2), MrE[j + 2], a2);
          a3 = fmaf(rlane(E, j + 3), MrE[j + 3], a3);
          a4 = fmaf(rlane(E, j + 4), MrE[j + 4], a4);
        }
        float acc = ((a0 + a1) + (a2 + a3)) + a4;
        bwd = (lane < 25) ? ms + __logf(acc) : NEGINF;
        em = emn;
      }
      if (lane < 25) bV[lane] = bwd;
    } else if (wid == 2) {
      float a = 0.f;
      const int* lb = labels + b * 512;
      for (int t = lane; t < 512; t += 64) a += nb[t * 25 + lb[t]];
      for (int t = lane; t < 511; t += 64) a += trans[lb[t] * 25 + lb[t + 1]];
      a = wsum(a);
      if (lane == 0) *s_num = a + startt[lb[0]] + endt[lb[511]];
    }
    __syncthreads();
    if (wid == 0) {
      float v = (lane < 25) ? fV[lane] + bV[lane] : NEGINF;
      float m = wmax(v);
      float ss = wsum(__expf(v - m));
      float llh = *s_num - (m + __logf(ss));
      if (lane == 0) atomicAdd(out, -llh * (1.f / 32.f));
    }
    return;
  }

  // ======== bidirectional Viterbi on softmax(cos_sim), batch b ========
  const int b = blk - 32;
  float* em = (float*)shraw;                     // [512][25] packed, 51200 B
  unsigned char* histF = shraw + 51200;          // [256][26]
  unsigned char* histB = shraw + 57856;          // [255][26]
  float* fV = (float*)(shraw + 64488);
  float* bV = fV + 32;
  const float* cb = cosim + (size_t)b * 512 * 25;

  {
    float4* em4 = (float4*)em;
    const float4* cb4 = (const float4*)cb;
    for (int i = tid; i < 3200; i += 256) em4[i] = cb4[i];
  }
  __syncthreads();
#pragma unroll
  for (int rr = 0; rr < 2; rr++) {
    const int r = tid + (rr << 8);
    float v[25];
#pragma unroll
    for (int k = 0; k < 25; k++) v[k] = em[r * 25 + k];
    float m01 = v[0];
#pragma unroll
    for (int k = 1; k < 25; k++) m01 = fmaxf(m01, v[k]);
    float s = 0.f;
#pragma unroll
    for (int k = 0; k < 25; k++) { v[k] = __expf(v[k] - m01); s += v[k]; }
    float rinv = __builtin_amdgcn_rcpf(s);
#pragma unroll
    for (int k = 0; k < 25; k++) em[r * 25 + k] = v[k] * rinv;
  }
  __syncthreads();

  const int eml = (lane < 25) ? lane : 0;
  if (wid == 0) {
    float Tc[25];  // trans[i][lane]
#pragma unroll
    for (int i = 0; i < 25; i++) Tc[i] = (lane < 25) ? trans[i * 25 + lane] : 0.f;
    float sc = (lane < 25) ? startt[lane] + em[eml] : NEGINF;
    float emA = em[25 + eml];
    for (int t = 1; t <= 256; t++) {
      float emB = (t < 256) ? em[(t + 1) * 25 + eml] : 0.f;
      float c[25];
#pragma unroll
      for (int i = 0; i < 25; i++) c[i] = rlane(sc, i) + Tc[i];
      float bv; int bi;
      argmax25(c, bv, bi);
      if (lane < 25) histF[(t - 1) * 26 + lane] = (unsigned char)bi;
      sc = (lane < 25) ? bv + emA : NEGINF;
      emA = emB;
    }
    if (lane < 25) fV[lane] = sc;
  } else if (wid == 1) {
    float Tr[25];  // trans[lane][j]
#pragma unroll
    for (int j = 0; j < 25; j++) Tr[j] = (lane < 25) ? trans[lane * 25 + j] : 0.f;
    float bwd = (lane < 25) ? endt[lane] : NEGINF;
    float emA = em[511 * 25 + eml];
    for (int t = 511; t >= 257; t--) {
      float emB = (t > 257) ? em[(t - 1) * 25 + eml] : 0.f;
      float u = bwd + emA;
      float c[25];
#pragma unroll
      for (int j = 0; j < 25; j++) c[j] = rlane(u, j) + Tr[j];
      float bv; int bj;
      argmax25(c, bv, bj);
      if (lane < 25) histB[(t - 1 - 256) * 26 + lane] = (unsigned char)bj;
      bwd = (lane < 25) ? bv : NEGINF;
      emA = emB;
    }
    if (lane < 25) bV[lane] = bwd;
  }
  __syncthreads();
  if (wid <= 1) {
    float fv = (lane < 25) ? fV[lane] + bV[lane] : NEGINF;
    int idx = lane;
#pragma unroll
    for (int m = 32; m >= 1; m >>= 1) {
      float ov = __shfl_xor(fv, m); int oi = __shfl_xor(idx, m);
      if (ov > fv || (ov == fv && oi < idx)) { fv = ov; idx = oi; }
    }
    int cur = idx;  // uniform
    float* path = out + 1 + (size_t)b * 512;
    if (wid == 0) {
      if (lane == 0) path[256] = (float)cur;
      int h = (lane < 25) ? histF[255 * 26 + lane] : 0;
      for (int t = 256; t >= 1; t--) {
        int hn = (t > 1 && lane < 25) ? histF[(t - 2) * 26 + lane] : 0;
        int prev = __builtin_amdgcn_readlane(h, cur);
        if (lane == 0) path[t - 1] = (float)prev;
        cur = prev; h = hn;
      }
    } else {
      int h = (lane < 25) ? histB[lane] : 0;
      for (int t = 256; t <= 510; t++) {
        int hn = (t < 510 && lane < 25) ? histB[(t - 255) * 26 + lane] : 0;
        int nx = __builtin_amdgcn_readlane(h, cur);
        if (lane == 0) path[t + 1] = (float)nx;
        cur = nx; h = hn;
      }
    }
  }
}

extern "C" void kernel_launch(void* const* d_in, const int* in_sizes, int n_in,
                              void* d_out, int out_size, void* d_ws, size_t ws_size,
                              hipStream_t stream) {
  (void)in_sizes; (void)n_in; (void)out_size; (void)ws_size;
  const float* bert   = (const float*)d_in[0];
  const float* oenc   = (const float*)d_in[1];
  const float* cosim  = (const float*)d_in[2];
  const float* decemb = (const float*)d_in[3];
  const int*   labels = (const int*)d_in[4];
  const float* gamma  = (const float*)d_in[5];
  const float* beta   = (const float*)d_in[6];
  const float* Wadd   = (const float*)d_in[7];
  const float* badd   = (const float*)d_in[8];
  const float* startt = (const float*)d_in[9];
  const float* endt   = (const float*)d_in[10];
  const float* trans  = (const float*)d_in[11];
  float* out = (float*)d_out;
  char*  wsb = (char*)d_ws;
  ushort* decb = (ushort*)wsb;                    // [0, 1228800)
  float*  wt   = (float*)(wsb + 1228800);         // [1228800, 1305600)
  float*  ner  = (float*)(wsb + 1305600);         // [1305600, 2944000)
  ushort* pqb  = (ushort*)(wsb + 2944000);        // [2944000, 28109824)

  prep_kernel<<<832, 256, 0, stream>>>(decemb, gamma, beta, Wadd, decb, wt);
  pq_kernel<<<1024, 256, 0, stream>>>(cosim, decb, pqb);
  main_kernel<<<2048, 256, 0, stream>>>(bert, oenc, pqb, gamma, beta, badd, wt, ner, out);
  scan_kernel<<<64, 256, 0, stream>>>(ner, cosim, labels, startt, endt, trans, out);
}

// Round 7
// 161.036 us; speedup vs baseline: 1.2585x; 1.2585x over previous
//
#include <hip/hip_runtime.h>
#include <hip/hip_bf16.h>

// NerTr fused pipeline for MI355X (gfx950).  B=32, S=512, D=768, C=25.
// ws layout (bytes): decb (bf16 32*25*768) [0, 1228800); wt (f32 25*768) [1228800, 1305600);
//                    ner (f32 32*512*25) [1305600, 2944000); pqb (bf16 32*512*768) [2944000, 28109824).
// out: [0]=loss (f32), [1 + b*512 + t] = viterbi tag (as f32).

#define NEGINF (-1e30f)

__device__ __forceinline__ float wsum(float v) {
#pragma unroll
  for (int m = 32; m >= 1; m >>= 1) v += __shfl_xor(v, m);
  return v;
}
__device__ __forceinline__ float wmax(float v) {
#pragma unroll
  for (int m = 32; m >= 1; m >>= 1) v = fmaxf(v, __shfl_xor(v, m));
  return v;
}
// SALU broadcast of lane0 (no LDS pipe)
__device__ __forceinline__ float rfl(float x) {
  return __int_as_float(__builtin_amdgcn_readfirstlane(__float_as_int(x)));
}
// uniform readlane (VALU->SGPR, no LDS pipe)
__device__ __forceinline__ float rlane(float x, int i) {
  return __int_as_float(__builtin_amdgcn_readlane(__float_as_int(x), i));
}
__device__ __forceinline__ ushort f2bf(float x) {
  __hip_bfloat16 h = __float2bfloat16(x);  // RTNE
  return *reinterpret_cast<ushort*>(&h);
}
// 12 contiguous-by-lane floats: elements (lane + k*64)*4 .. +3
__device__ __forceinline__ void ld12(float* x, const float* p, int lane) {
#pragma unroll
  for (int k = 0; k < 3; k++) {
    float4 v = *(const float4*)(p + (lane + (k << 6)) * 4);
    x[4 * k + 0] = v.x; x[4 * k + 1] = v.y; x[4 * k + 2] = v.z; x[4 * k + 3] = v.w;
  }
}

// in-register argmax over 25 values, first-index tie-break (jnp.argmax semantics)
__device__ __forceinline__ void argmax25(const float c[25], float& bv, int& bi) {
  float v[13]; int x[13];
#pragma unroll
  for (int i = 0; i < 12; i++) {
    bool t = c[2 * i + 1] > c[2 * i];
    v[i] = t ? c[2 * i + 1] : c[2 * i];
    x[i] = t ? 2 * i + 1 : 2 * i;
  }
  v[12] = c[24]; x[12] = 24;
  float w[7]; int y[7];
#pragma unroll
  for (int i = 0; i < 6; i++) {
    bool t = v[2 * i + 1] > v[2 * i];
    w[i] = t ? v[2 * i + 1] : v[2 * i];
    y[i] = t ? x[2 * i + 1] : x[2 * i];
  }
  w[6] = v[12]; y[6] = x[12];
  float u[4]; int z[4];
#pragma unroll
  for (int i = 0; i < 3; i++) {
    bool t = w[2 * i + 1] > w[2 * i];
    u[i] = t ? w[2 * i + 1] : w[2 * i];
    z[i] = t ? y[2 * i + 1] : y[2 * i];
  }
  u[3] = w[6]; z[3] = y[6];
  bool t0 = u[1] > u[0]; float a = t0 ? u[1] : u[0]; int ai = t0 ? z[1] : z[0];
  bool t1 = u[3] > u[2]; float b = t1 ? u[3] : u[2]; int bj = t1 ? z[3] : z[2];
  bool t2 = b > a; bv = t2 ? b : a; bi = t2 ? bj : ai;
}

// ---------------- Kernel 1: LN(decoder_embedding)->bf16 + transpose W ----------------
__global__ __launch_bounds__(256) void prep_kernel(
    const float* __restrict__ decemb, const float* __restrict__ gamma,
    const float* __restrict__ beta, const float* __restrict__ Wadd,
    ushort* __restrict__ decb, float* __restrict__ wt) {
  const int blk = blockIdx.x;
  const int tid = threadIdx.x;
  if (blk < 800) {  // one block per (b,c) row of decoder_embedding
    const float* in = decemb + (size_t)blk * 768;
    float x0 = in[tid], x1 = in[tid + 256], x2 = in[tid + 512];
    float s = x0 + x1 + x2, q = x0 * x0 + x1 * x1 + x2 * x2;
    float ws_ = wsum(s), wq = wsum(q);
    __shared__ float sa[4], sq[4];
    int w = tid >> 6, ln = tid & 63;
    if (ln == 0) { sa[w] = ws_; sq[w] = wq; }
    __syncthreads();
    float s1 = sa[0] + sa[1] + sa[2] + sa[3];
    float s2 = sq[0] + sq[1] + sq[2] + sq[3];
    float mean = s1 * (1.f / 768.f);
    float rstd = rsqrtf(s2 * (1.f / 768.f) - mean * mean + 1e-5f);
    ushort* o = decb + (size_t)blk * 768;
    o[tid]       = f2bf((x0 - mean) * rstd * gamma[tid]       + beta[tid]);
    o[tid + 256] = f2bf((x1 - mean) * rstd * gamma[tid + 256] + beta[tid + 256]);
    o[tid + 512] = f2bf((x2 - mean) * rstd * gamma[tid + 512] + beta[tid + 512]);
  } else {  // transpose W_add [768,25] -> Wt [25,768]
    int gid = (blk - 800) * 256 + tid;
    for (int e = gid; e < 19200; e += 32 * 256) {
      int d = e / 25, j = e - d * 25;
      wt[j * 768 + d] = Wadd[e];
    }
  }
}

// ---------------- Kernel 2: pq = cos_sim @ dec  -> bf16 (LDS-staged dec, 4 rows/wave) ----------------
__global__ __launch_bounds__(256) void pq_kernel(
    const float* __restrict__ cosim, const ushort* __restrict__ decb,
    ushort* __restrict__ pqb) {
  __shared__ ushort sdec[19200];  // dec[b] bf16, 38400 B
  const int tid = threadIdx.x;
  const int lane = tid & 63;
  const int wid = tid >> 6;
  // bijective XCD swizzle (1024 = 8 x 128)
  const int swz = (blockIdx.x & 7) * 128 + (blockIdx.x >> 3);
  const int b = swz >> 5;                              // 32 blocks per batch
  const int row0 = ((swz & 31) << 4) + (wid << 2);     // 16 rows/block, 4/wave
  const int rowg = b * 512 + row0;

  {
    const uint4* src = (const uint4*)(decb + (size_t)b * 19200);
    uint4* dst = (uint4*)sdec;
#pragma unroll
    for (int i = 0; i < 10; i++) {
      int e = tid + (i << 8);
      if (e < 2400) dst[e] = src[e];
    }
  }
  float cs[4];
#pragma unroll
  for (int r = 0; r < 4; r++)
    cs[r] = (lane < 25) ? cosim[(size_t)(rowg + r) * 25 + lane] : 0.f;
  __syncthreads();

  float pq[4][12];
#pragma unroll
  for (int r = 0; r < 4; r++)
#pragma unroll
    for (int e = 0; e < 12; e++) pq[r][e] = 0.f;
  const char* sd = (const char*)sdec;
#pragma unroll 5
  for (int c = 0; c < 25; c++) {
    uint2 d0 = *(const uint2*)(sd + c * 1536 + lane * 8);
    uint2 d1 = *(const uint2*)(sd + c * 1536 + lane * 8 + 512);
    uint2 d2 = *(const uint2*)(sd + c * 1536 + lane * 8 + 1024);
    float dv[12];
    dv[0]  = __uint_as_float(d0.x << 16); dv[1]  = __uint_as_float(d0.x & 0xffff0000u);
    dv[2]  = __uint_as_float(d0.y << 16); dv[3]  = __uint_as_float(d0.y & 0xffff0000u);
    dv[4]  = __uint_as_float(d1.x << 16); dv[5]  = __uint_as_float(d1.x & 0xffff0000u);
    dv[6]  = __uint_as_float(d1.y << 16); dv[7]  = __uint_as_float(d1.y & 0xffff0000u);
    dv[8]  = __uint_as_float(d2.x << 16); dv[9]  = __uint_as_float(d2.x & 0xffff0000u);
    dv[10] = __uint_as_float(d2.y << 16); dv[11] = __uint_as_float(d2.y & 0xffff0000u);
    float f0 = rlane(cs[0], c), f1 = rlane(cs[1], c);
    float f2 = rlane(cs[2], c), f3 = rlane(cs[3], c);
#pragma unroll
    for (int e = 0; e < 12; e++) {
      pq[0][e] = fmaf(f0, dv[e], pq[0][e]);
      pq[1][e] = fmaf(f1, dv[e], pq[1][e]);
      pq[2][e] = fmaf(f2, dv[e], pq[2][e]);
      pq[3][e] = fmaf(f3, dv[e], pq[3][e]);
    }
  }
  // write bf16, layout matches ld12's (lane + k*64)*4 element order
#pragma unroll
  for (int r = 0; r < 4; r++) {
    ushort* pr = pqb + (size_t)(rowg + r) * 768;
#pragma unroll
    for (int k = 0; k < 3; k++) {
      uint2 u;
      u.x = (uint)f2bf(pq[r][4 * k + 0]) | ((uint)f2bf(pq[r][4 * k + 1]) << 16);
      u.y = (uint)f2bf(pq[r][4 * k + 2]) | ((uint)f2bf(pq[r][4 * k + 3]) << 16);
      *(uint2*)(pr + (lane + (k << 6)) * 4) = u;
    }
  }
}

// ---------------- Kernel 3: streaming LN/add/LN/logits (2 rows/wave, NO register arrays in D) ----------------
__global__ __launch_bounds__(256) void main_kernel(
    const float* __restrict__ bert, const float* __restrict__ oenc,
    const ushort* __restrict__ pqb, const float* __restrict__ gamma,
    const float* __restrict__ beta, const float* __restrict__ badd,
    const float* __restrict__ wt,
    float* __restrict__ ner, float* __restrict__ out) {
  __shared__ ushort sred[4][2][1700];  // per-wave, per-row [25][68] bf16 scratch (27.2 KB)
  const int tid = threadIdx.x;
  const int lane = tid & 63;
  const int wid = tid >> 6;
  if (blockIdx.x == 0 && tid == 0) out[0] = 0.f;  // loss accumulator (scan adds later)

  // bijective XCD swizzle (2048 = 8 x 256)
  const int swz = (blockIdx.x & 7) * 256 + (blockIdx.x >> 3);
  const int b = swz >> 6;
  const int rowg = b * 512 + ((swz & 63) << 3) + (wid << 1);  // 8 rows/block, 2/wave

  float g[12], bbv[12];
  ld12(g, gamma, lane);
  ld12(bbv, beta, lane);

  float acc[2][12];
  ld12(acc[0], bert + (size_t)(rowg + 0) * 768, lane);
  ld12(acc[1], bert + (size_t)(rowg + 1) * 768, lane);

  // Phase A: acc = LN(bert)
#pragma unroll
  for (int r = 0; r < 2; r++) {
    float s = 0.f, q = 0.f;
#pragma unroll
    for (int e = 0; e < 12; e++) { s += acc[r][e]; q += acc[r][e] * acc[r][e]; }
    s = wsum(s); q = wsum(q);
    float mean = s * (1.f / 768.f);
    float rstd = rsqrtf(q * (1.f / 768.f) - mean * mean + 1e-5f);
#pragma unroll
    for (int e = 0; e < 12; e++) acc[r][e] = (acc[r][e] - mean) * rstd * g[e] + bbv[e];
  }

  // += oenc (sequential: y dies after each add)
#pragma unroll
  for (int r = 0; r < 2; r++) {
    float y[12];
    ld12(y, oenc + (size_t)(rowg + r) * 768, lane);
#pragma unroll
    for (int e = 0; e < 12; e++) acc[r][e] += y[e];
  }
  // += pq (bf16)
#pragma unroll
  for (int r = 0; r < 2; r++) {
    const ushort* pr = pqb + (size_t)(rowg + r) * 768;
#pragma unroll
    for (int k = 0; k < 3; k++) {
      uint2 u = *(const uint2*)(pr + (lane + (k << 6)) * 4);
      acc[r][4 * k + 0] += __uint_as_float(u.x << 16);
      acc[r][4 * k + 1] += __uint_as_float(u.x & 0xffff0000u);
      acc[r][4 * k + 2] += __uint_as_float(u.y << 16);
      acc[r][4 * k + 3] += __uint_as_float(u.y & 0xffff0000u);
    }
  }

  // Phase C: acc = relu(LN(acc))
#pragma unroll
  for (int r = 0; r < 2; r++) {
    float s = 0.f, q = 0.f;
#pragma unroll
    for (int e = 0; e < 12; e++) { s += acc[r][e]; q += acc[r][e] * acc[r][e]; }
    s = wsum(s); q = wsum(q);
    float mean = s * (1.f / 768.f);
    float rstd = rsqrtf(q * (1.f / 768.f) - mean * mean + 1e-5f);
#pragma unroll
    for (int e = 0; e < 12; e++)
      acc[r][e] = fmaxf((acc[r][e] - mean) * rstd * g[e] + bbv[e], 0.f);
  }

  // Phase D: logits j-loop with IMMEDIATE LDS scatter — no p[2][25] register array,
  // so runtime j never demotes anything to scratch (rule #20).
  ushort* scw0 = sred[wid][0];
  ushort* scw1 = sred[wid][1];
  for (int j = 0; j < 25; j++) {
    float wv[12];
    ld12(wv, wt + j * 768, lane);
    float p0 = 0.f, p1 = 0.f;
#pragma unroll
    for (int e = 0; e < 12; e++) {
      p0 = fmaf(acc[0][e], wv[e], p0);
      p1 = fmaf(acc[1][e], wv[e], p1);
    }
    scw0[j * 68 + lane] = f2bf(p0);
    scw1[j * 68 + lane] = f2bf(p1);
  }
  // wave-synchronous reduce (LDS ops within a wave are program-ordered; proven r4-r6)
  float bav = (lane < 25) ? badd[lane] : 0.f;
  const int jj = (lane < 25) ? lane : 24;
#pragma unroll
  for (int r = 0; r < 2; r++) {
    const ushort* scw = sred[wid][r];
    float lg = bav;
#pragma unroll
    for (int i = 0; i < 16; i++) {
      uint2 u = *(const uint2*)(scw + jj * 68 + i * 4);
      lg += __uint_as_float(u.x << 16);
      lg += __uint_as_float(u.x & 0xffff0000u);
      lg += __uint_as_float(u.y << 16);
      lg += __uint_as_float(u.y & 0xffff0000u);
    }
    float v = (lane < 25) ? lg : NEGINF;
    float m = wmax(v);
    float e = __expf(v - m);
    float s = wsum(e);
    float lp = v - m - __logf(s);
    if (lane < 25) ner[(size_t)(rowg + r) * 25 + lane] = lp;
  }
}

// ---------------- Kernel 4: CRF (blocks 0..31) + Viterbi (blocks 32..63) ----------------
// All sequential chains use v_readlane (VALU) — zero ds_bpermute on the critical path.
__global__ __launch_bounds__(256) void scan_kernel(
    const float* __restrict__ ner, const float* __restrict__ cosim,
    const int* __restrict__ labels,
    const float* __restrict__ startt, const float* __restrict__ endt,
    const float* __restrict__ trans, float* __restrict__ out) {
  const int tid = threadIdx.x, lane = tid & 63, wid = tid >> 6;
  const int blk = blockIdx.x;
  __shared__ __align__(16) unsigned char shraw[64768];

  if (blk < 32) {
    // ======== CRF NLL for batch b ========
    const int b = blk;
    const float* nb = ner + (size_t)b * 512 * 25;
    float* fV = (float*)shraw;
    float* bV = fV + 32;
    float* s_num = bV + 32;
    if (wid == 0) {
      float Mc[25];  // exp(trans[i][lane])
#pragma unroll
      for (int i = 0; i < 25; i++) Mc[i] = (lane < 25) ? __expf(trans[i * 25 + lane]) : 0.f;
      float sc = (lane < 25) ? startt[lane] + nb[lane] : NEGINF;
      float em = (lane < 25) ? nb[25 + lane] : 0.f;
      for (int t = 1; t <= 256; t++) {
        float emn = (t < 256 && lane < 25) ? nb[(t + 1) * 25 + lane] : 0.f;
        float ms = rfl(sc);
        float E = __expf(sc - ms);
        float a0 = 0, a1 = 0, a2 = 0, a3 = 0, a4 = 0;
#pragma unroll
        for (int i = 0; i < 25; i += 5) {
          a0 = fmaf(rlane(E, i + 0), Mc[i + 0], a0);
          a1 = fmaf(rlane(E, i + 1), Mc[i + 1], a1);
          a2 = fmaf(rlane(E, i + 2), Mc[i + 2], a2);
          a3 = fmaf(rlane(E, i + 3), Mc[i + 3], a3);
          a4 = fmaf(rlane(E, i + 4), Mc[i + 4], a4);
        }
        float acc = ((a0 + a1) + (a2 + a3)) + a4;
        sc = (lane < 25) ? ms + __logf(acc) + em : NEGINF;
        em = emn;
      }
      if (lane < 25) fV[lane] = sc;
    } else if (wid == 1) {
      float MrE[25];  // exp(trans[lane][j])
#pragma unroll
      for (int j = 0; j < 25; j++) MrE[j] = (lane < 25) ? __expf(trans[lane * 25 + j]) : 0.f;
      float bwd = (lane < 25) ? endt[lane] : NEGINF;
      float em = (lane < 25) ? nb[511 * 25 + lane] : 0.f;
      for (int t = 511; t >= 257; t--) {
        float emn = (t > 257 && lane < 25) ? nb[(t - 1) * 25 + lane] : 0.f;
        float u = (lane < 25) ? bwd + em : NEGINF;
        float ms = rfl(u);
        float E = __expf(u - ms);
        float a0 = 0, a1 = 0, a2 = 0, a3 = 0, a4 = 0;
#pragma unroll
        for (int j = 0; j < 25; j += 5) {
          a0 = fmaf(rlane(E, j + 0), MrE[j + 0], a0);
          a1 = fmaf(rlane(E, j + 1), MrE[j + 1], a1);
          a2 = fmaf(rlane(E, j + 2), MrE[j + 2], a2);
          a3 = fmaf(rlane(E, j + 3), MrE[j + 3], a3);
          a4 = fmaf(rlane(E, j + 4), MrE[j + 4], a4);
        }
        float acc = ((a0 + a1) + (a2 + a3)) + a4;
        bwd = (lane < 25) ? ms + __logf(acc) : NEGINF;
        em = emn;
      }
      if (lane < 25) bV[lane] = bwd;
    } else if (wid == 2) {
      float a = 0.f;
      const int* lb = labels + b * 512;
      for (int t = lane; t < 512; t += 64) a += nb[t * 25 + lb[t]];
      for (int t = lane; t < 511; t += 64) a += trans[lb[t] * 25 + lb[t + 1]];
      a = wsum(a);
      if (lane == 0) *s_num = a + startt[lb[0]] + endt[lb[511]];
    }
    __syncthreads();
    if (wid == 0) {
      float v = (lane < 25) ? fV[lane] + bV[lane] : NEGINF;
      float m = wmax(v);
      float ss = wsum(__expf(v - m));
      float llh = *s_num - (m + __logf(ss));
      if (lane == 0) atomicAdd(out, -llh * (1.f / 32.f));
    }
    return;
  }

  // ======== bidirectional Viterbi on softmax(cos_sim), batch b ========
  const int b = blk - 32;
  float* em = (float*)shraw;                     // [512][25] packed, 51200 B
  unsigned char* histF = shraw + 51200;          // [256][26]
  unsigned char* histB = shraw + 57856;          // [255][26]
  float* fV = (float*)(shraw + 64488);
  float* bV = fV + 32;
  const float* cb = cosim + (size_t)b * 512 * 25;

  {
    float4* em4 = (float4*)em;
    const float4* cb4 = (const float4*)cb;
    for (int i = tid; i < 3200; i += 256) em4[i] = cb4[i];
  }
  __syncthreads();
#pragma unroll
  for (int rr = 0; rr < 2; rr++) {
    const int r = tid + (rr << 8);
    float v[25];
#pragma unroll
    for (int k = 0; k < 25; k++) v[k] = em[r * 25 + k];
    float m01 = v[0];
#pragma unroll
    for (int k = 1; k < 25; k++) m01 = fmaxf(m01, v[k]);
    float s = 0.f;
#pragma unroll
    for (int k = 0; k < 25; k++) { v[k] = __expf(v[k] - m01); s += v[k]; }
    float rinv = __builtin_amdgcn_rcpf(s);
#pragma unroll
    for (int k = 0; k < 25; k++) em[r * 25 + k] = v[k] * rinv;
  }
  __syncthreads();

  const int eml = (lane < 25) ? lane : 0;
  if (wid == 0) {
    float Tc[25];  // trans[i][lane]
#pragma unroll
    for (int i = 0; i < 25; i++) Tc[i] = (lane < 25) ? trans[i * 25 + lane] : 0.f;
    float sc = (lane < 25) ? startt[lane] + em[eml] : NEGINF;
    float emA = em[25 + eml];
    for (int t = 1; t <= 256; t++) {
      float emB = (t < 256) ? em[(t + 1) * 25 + eml] : 0.f;
      float c[25];
#pragma unroll
      for (int i = 0; i < 25; i++) c[i] = rlane(sc, i) + Tc[i];
      float bv; int bi;
      argmax25(c, bv, bi);
      if (lane < 25) histF[(t - 1) * 26 + lane] = (unsigned char)bi;
      sc = (lane < 25) ? bv + emA : NEGINF;
      emA = emB;
    }
    if (lane < 25) fV[lane] = sc;
  } else if (wid == 1) {
    float Tr[25];  // trans[lane][j]
#pragma unroll
    for (int j = 0; j < 25; j++) Tr[j] = (lane < 25) ? trans[lane * 25 + j] : 0.f;
    float bwd = (lane < 25) ? endt[lane] : NEGINF;
    float emA = em[511 * 25 + eml];
    for (int t = 511; t >= 257; t--) {
      float emB = (t > 257) ? em[(t - 1) * 25 + eml] : 0.f;
      float u = bwd + emA;
      float c[25];
#pragma unroll
      for (int j = 0; j < 25; j++) c[j] = rlane(u, j) + Tr[j];
      float bv; int bj;
      argmax25(c, bv, bj);
      if (lane < 25) histB[(t - 1 - 256) * 26 + lane] = (unsigned char)bj;
      bwd = (lane < 25) ? bv : NEGINF;
      emA = emB;
    }
    if (lane < 25) bV[lane] = bwd;
  }
  __syncthreads();
  if (wid <= 1) {
    float fv = (lane < 25) ? fV[lane] + bV[lane] : NEGINF;
    int idx = lane;
#pragma unroll
    for (int m = 32; m >= 1; m >>= 1) {
      float ov = __shfl_xor(fv, m); int oi = __shfl_xor(idx, m);
      if (ov > fv || (ov == fv && oi < idx)) { fv = ov; idx = oi; }
    }
    int cur = idx;  // uniform
    float* path = out + 1 + (size_t)b * 512;
    if (wid == 0) {
      if (lane == 0) path[256] = (float)cur;
      int h = (lane < 25) ? histF[255 * 26 + lane] : 0;
      for (int t = 256; t >= 1; t--) {
        int hn = (t > 1 && lane < 25) ? histF[(t - 2) * 26 + lane] : 0;
        int prev = __builtin_amdgcn_readlane(h, cur);
        if (lane == 0) path[t - 1] = (float)prev;
        cur = prev; h = hn;
      }
    } else {
      int h = (lane < 25) ? histB[lane] : 0;
      for (int t = 256; t <= 510; t++) {
        int hn = (t < 510 && lane < 25) ? histB[(t - 255) * 26 + lane] : 0;
        int nx = __builtin_amdgcn_readlane(h, cur);
        if (lane == 0) path[t + 1] = (float)nx;
        cur = nx; h = hn;
      }
    }
  }
}

extern "C" void kernel_launch(void* const* d_in, const int* in_sizes, int n_in,
                              void* d_out, int out_size, void* d_ws, size_t ws_size,
                              hipStream_t stream) {
  (void)in_sizes; (void)n_in; (void)out_size; (void)ws_size;
  const float* bert   = (const float*)d_in[0];
  const float* oenc   = (const float*)d_in[1];
  const float* cosim  = (const float*)d_in[2];
  const float* decemb = (const float*)d_in[3];
  const int*   labels = (const int*)d_in[4];
  const float* gamma  = (const float*)d_in[5];
  const float* beta   = (const float*)d_in[6];
  const float* Wadd   = (const float*)d_in[7];
  const float* badd   = (const float*)d_in[8];
  const float* startt = (const float*)d_in[9];
  const float* endt   = (const float*)d_in[10];
  const float* trans  = (const float*)d_in[11];
  float* out = (float*)d_out;
  char*  wsb = (char*)d_ws;
  ushort* decb = (ushort*)wsb;                    // [0, 1228800)
  float*  wt   = (float*)(wsb + 1228800);         // [1228800, 1305600)
  float*  ner  = (float*)(wsb + 1305600);         // [1305600, 2944000)
  ushort* pqb  = (ushort*)(wsb + 2944000);        // [2944000, 28109824)

  prep_kernel<<<832, 256, 0, stream>>>(decemb, gamma, beta, Wadd, decb, wt);
  pq_kernel<<<1024, 256, 0, stream>>>(cosim, decb, pqb);
  main_kernel<<<2048, 256, 0, stream>>>(bert, oenc, pqb, gamma, beta, badd, wt, ner, out);
  scan_kernel<<<64, 256, 0, stream>>>(ner, cosim, labels, startt, endt, trans, out);
}